// Round 13
// baseline (93.437 us; speedup 1.0000x reference)
//
#include <hip/hip_runtime.h>
#include <hip/hip_bf16.h>

#define BATCH  4096
#define DIM    1024
#define NCHUNK 16          // 256-col chunks per row in STATS
#define BM     256
#define BN     256
#define BKK    64
#define NKT    (DIM / BKK) // 16 K-tiles
#define INVT   14.285714285714286f
#define C1     20.609929f  // INVT * log2(e); exp(INVT*(d-1)) == exp2(d*C1 - C1)
#define EPSV   1e-8f
#define NEGINF -3.0e38f

typedef __bf16 bf16x8 __attribute__((ext_vector_type(8)));
typedef float  f32x4  __attribute__((ext_vector_type(4)));
typedef __attribute__((address_space(3))) void lds_void;
typedef __attribute__((address_space(1))) void gl_void;

// Branchless sorted-desc top-5 insert (9 min/max ops).
__device__ __forceinline__ void top5_insert(float (&t)[5], float v) {
  float a = fmaxf(t[4], v), b;
  b = t[3]; t[4] = fminf(b, a); a = fmaxf(b, a);
  b = t[2]; t[3] = fminf(b, a); a = fmaxf(b, a);
  b = t[1]; t[2] = fminf(b, a); a = fmaxf(b, a);
  b = t[0]; t[1] = fminf(b, a); t[0] = fmaxf(b, a);
}

__device__ __forceinline__ void ce_desc(float& a, float& b) {
  const float hi = fmaxf(a, b), lo = fminf(a, b);
  a = hi; b = lo;
}

// Merge sorted-desc top5 with lane^msk's: elementwise max vs reversed partner
// list = top-5 multiset; 9-CE network re-sorts.
__device__ __forceinline__ void top5_merge_x(float (&t)[5], int msk) {
  const float b0 = __shfl_xor(t[0], msk);
  const float b1 = __shfl_xor(t[1], msk);
  const float b2 = __shfl_xor(t[2], msk);
  const float b3 = __shfl_xor(t[3], msk);
  const float b4 = __shfl_xor(t[4], msk);
  t[0] = fmaxf(t[0], b4); t[1] = fmaxf(t[1], b3); t[2] = fmaxf(t[2], b2);
  t[3] = fmaxf(t[3], b1); t[4] = fmaxf(t[4], b0);
  ce_desc(t[0], t[1]); ce_desc(t[3], t[4]); ce_desc(t[2], t[4]);
  ce_desc(t[2], t[3]); ce_desc(t[1], t[4]); ce_desc(t[0], t[3]);
  ce_desc(t[0], t[2]); ce_desc(t[1], t[3]); ce_desc(t[1], t[2]);
}

// ---------------- kernel 0: label histogram ----------------
__global__ __launch_bounds__(1024) void k_hist(const long long* __restrict__ LAB,
                                               int* __restrict__ HIST) {
  __shared__ int h[512];
  const int t = threadIdx.x;
  if (t < 512) h[t] = 0;
  __syncthreads();
  for (int i = t; i < BATCH; i += 1024) atomicAdd(&h[(int)LAB[i]], 1);
  __syncthreads();
  if (t < 512) HIST[t] = h[t];
}

// ---------------- kernel 1: row L2-normalize fp32 -> bf16 (+ bf16 self-dot) ----------------
__global__ __launch_bounds__(256) void k_normalize(const float* __restrict__ X,
                                                   unsigned short* __restrict__ F,
                                                   float* __restrict__ DDIAG) {
  const int row = blockIdx.x;
  const int t = threadIdx.x;
  const float4 v = ((const float4*)(X + (size_t)row * DIM))[t];
  float ss = v.x*v.x + v.y*v.y + v.z*v.z + v.w*v.w;
#pragma unroll
  for (int m = 32; m >= 1; m >>= 1) ss += __shfl_xor(ss, m);
  __shared__ float wsum[4], wsum2[4];
  if ((t & 63) == 0) wsum[t >> 6] = ss;
  __syncthreads();
  const float tot = wsum[0] + wsum[1] + wsum[2] + wsum[3];
  const float inv = 1.0f / fmaxf(sqrtf(tot), 1e-12f);
  const __bf16 b0 = (__bf16)(v.x * inv), b1 = (__bf16)(v.y * inv);
  const __bf16 b2 = (__bf16)(v.z * inv), b3 = (__bf16)(v.w * inv);
  const float f0 = (float)b0, f1 = (float)b1, f2 = (float)b2, f3 = (float)b3;
  float s2 = f0*f0 + f1*f1 + f2*f2 + f3*f3;
#pragma unroll
  for (int m = 32; m >= 1; m >>= 1) s2 += __shfl_xor(s2, m);
  if ((t & 63) == 0) wsum2[t >> 6] = s2;
  ushort4 o;
  o.x = __builtin_bit_cast(unsigned short, b0);
  o.y = __builtin_bit_cast(unsigned short, b1);
  o.z = __builtin_bit_cast(unsigned short, b2);
  o.w = __builtin_bit_cast(unsigned short, b3);
  ((ushort4*)(F + (size_t)row * DIM))[t] = o;
  __syncthreads();
  if (t == 0) DDIAG[row] = wsum2[0] + wsum2[1] + wsum2[2] + wsum2[3];
}

// ---------------- kernel 2: fused sim GEMM + stats (256x256, 8-phase COUNTED) ----------------
// m201-style schedule. Death-driven staging, per wave per iteration j:
//   ph1: issue A(2j+1)->lA[1]   (lA[1] last read ph8 of prev iter, drained)
//   ph4: issue B(2j+2)->lB[0]   (lB[0] last read ph3, drained)
//   ph5: issue A(2j+2)->lA[0]   (lA[0] last read ph4, drained)
//   ph8: issue B(2j+3)->lB[1]   (lB[1] last read ph7, drained)
// Counted waits ONLY at ph1/ph5: vmcnt(8) (16 max outstanding; the 8 needed
// loads are always the oldest). Every phase's ds_reads are lgkm-drained
// before its MFMAs (compiler dataflow), so a region's reads are complete
// once all waves pass that phase's trailing barrier — which precedes the
// next stage into it. Prologue stages B(0),A(0),B(1) with NO drain (iter-0
// ph1's vmcnt(8) covers it). Tail clamps kt to 15 (harmless re-stage of
// dead regions keeps wait counts uniform). Terminal vmcnt(0)+barrier before
// the LDS 'part' overlay.
__global__ __launch_bounds__(512) void k_fused(const unsigned short* __restrict__ F,
                                               const long long* __restrict__ LAB,
                                               float* __restrict__ STATS) {
  __shared__ __align__(16) unsigned short lA[2][BM * BKK];  // 2 x 32 KB
  __shared__ __align__(16) unsigned short lB[2][BN * BKK];  // 2 x 32 KB

  const int ch  = blockIdx.x;
  const int rb  = blockIdx.y;
  const int tid = threadIdx.x;
  const int l   = tid & 63;
  const int l15 = l & 15;
  const int l4  = l >> 4;
  const int wid = tid >> 6;
  const int wm  = wid >> 2;        // 0..1
  const int wn  = wid & 3;         // 0..3
  const int swz = (l15 & 7) << 4;  // XOR swizzle: row%8 == l15&7 for frag reads
  const int rowbase = rb * BM;
  const int colbase = ch * BN;

  f32x4 acc[8][4];
#pragma unroll
  for (int mf = 0; mf < 8; ++mf)
#pragma unroll
    for (int nf = 0; nf < 4; ++nf) acc[mf][nf] = (f32x4){0.f, 0.f, 0.f, 0.f};

  // Precomputed staging addresses (linear LDS dest, pre-swizzled global src:
  // 16B chunk c fetched from chunk c^(r&7), involution within the 128B row).
  const unsigned short* gArow[4];
  const unsigned short* gBrow[4];
  int ldso[4];
#pragma unroll
  for (int it = 0; it < 4; ++it) {
    const int s = it * 512 + tid;            // 16B slot (2048 per matrix)
    const int r = s >> 3;                    // row (8 chunks per 128B row)
    const int c = (s & 7) ^ (r & 7);         // source chunk (involution)
    ldso[it]  = s * 16;
    gArow[it] = F + (size_t)(rowbase + r) * DIM + c * 8;
    gBrow[it] = F + (size_t)(colbase + r) * DIM + c * 8;
  }

  auto stageA = [&](int buf, int kt) {
#pragma unroll
    for (int it = 0; it < 4; ++it)
      __builtin_amdgcn_global_load_lds((gl_void*)(gArow[it] + kt * BKK),
                                       (lds_void*)((char*)&lA[buf][0] + ldso[it]), 16, 0, 0);
  };
  auto stageB = [&](int buf, int kt) {
#pragma unroll
    for (int it = 0; it < 4; ++it)
      __builtin_amdgcn_global_load_lds((gl_void*)(gBrow[it] + kt * BKK),
                                       (lds_void*)((char*)&lB[buf][0] + ldso[it]), 16, 0, 0);
  };

#define DSREAD_BV(BUF, KK, BVARR)                                              \
  _Pragma("unroll")                                                            \
  for (int nf = 0; nf < 4; ++nf)                                               \
    BVARR[nf] = *(const bf16x8*)((const char*)&lB[BUF][0] +                    \
                 (wn * 64 + nf * 16 + l15) * 128 + (((KK)*64 + l4*16) ^ swz));

#define DSREAD_AV(BUF, M2, KK, AVARR)                                          \
  _Pragma("unroll")                                                            \
  for (int q = 0; q < 4; ++q)                                                  \
    AVARR[q] = *(const bf16x8*)((const char*)&lA[BUF][0] +                     \
                 (wm * 128 + ((M2)*4 + q) * 16 + l15) * 128 +                  \
                 (((KK)*64 + l4*16) ^ swz));

#define MFMA16(M2, AVARR, BVARR)                                               \
  __builtin_amdgcn_s_setprio(1);                                               \
  _Pragma("unroll")                                                            \
  for (int q = 0; q < 4; ++q)                                                  \
    _Pragma("unroll")                                                          \
    for (int nf = 0; nf < 4; ++nf)                                             \
      acc[(M2)*4 + q][nf] = __builtin_amdgcn_mfma_f32_16x16x32_bf16(           \
          AVARR[q], BVARR[nf], acc[(M2)*4 + q][nf], 0, 0, 0);                  \
  __builtin_amdgcn_s_setprio(0);

  // ---- prologue: B(0),A(0) -> buf0; B(1) -> lB[1]. No drain needed. ----
  stageB(0, 0);
  stageA(0, 0);
  stageB(1, 1);

#pragma unroll 1
  for (int j = 0; j < NKT / 2; ++j) {
    const int t2 = (2 * j + 2 < NKT) ? 2 * j + 2 : NKT - 1;  // clamped (tail dummy)
    const int t3 = (2 * j + 3 < NKT) ? 2 * j + 3 : NKT - 1;
    bf16x8 bv0[4], bv1[4], av[4];

    // ---- phase 1: stage A(2j+1)->lA[1]; vmcnt(8) gates tile 2j (oldest 8) ----
    stageA(1, 2 * j + 1);
    __builtin_amdgcn_sched_barrier(0);
    asm volatile("s_waitcnt vmcnt(8)" ::: "memory");
    __builtin_amdgcn_s_barrier();            // all waves' tile-2j loads landed
    DSREAD_BV(0, 0, bv0)
    DSREAD_AV(0, 0, 0, av)
    __builtin_amdgcn_s_barrier();
    MFMA16(0, av, bv0)
    __builtin_amdgcn_s_barrier();
    // ---- phase 2 ----
    DSREAD_AV(0, 1, 0, av)
    __builtin_amdgcn_s_barrier();
    MFMA16(1, av, bv0)
    __builtin_amdgcn_s_barrier();
    // ---- phase 3 (last lB[0] reads) ----
    DSREAD_BV(0, 1, bv1)
    DSREAD_AV(0, 0, 1, av)
    __builtin_amdgcn_s_barrier();
    MFMA16(0, av, bv1)
    __builtin_amdgcn_s_barrier();
    // ---- phase 4 (last lA[0] reads); stage B(t2)->lB[0] ----
    DSREAD_AV(0, 1, 1, av)
    stageB(0, t2);
    __builtin_amdgcn_s_barrier();
    MFMA16(1, av, bv1)
    __builtin_amdgcn_s_barrier();

    // ---- phase 5: stage A(t2)->lA[0]; vmcnt(8) gates tile 2j+1 ----
    stageA(0, t2);
    __builtin_amdgcn_sched_barrier(0);
    asm volatile("s_waitcnt vmcnt(8)" ::: "memory");
    __builtin_amdgcn_s_barrier();            // all waves' tile-2j+1 loads landed
    DSREAD_BV(1, 0, bv0)
    DSREAD_AV(1, 0, 0, av)
    __builtin_amdgcn_s_barrier();
    MFMA16(0, av, bv0)
    __builtin_amdgcn_s_barrier();
    // ---- phase 6 ----
    DSREAD_AV(1, 1, 0, av)
    __builtin_amdgcn_s_barrier();
    MFMA16(1, av, bv0)
    __builtin_amdgcn_s_barrier();
    // ---- phase 7 (last lB[1] reads) ----
    DSREAD_BV(1, 1, bv1)
    DSREAD_AV(1, 0, 1, av)
    __builtin_amdgcn_s_barrier();
    MFMA16(0, av, bv1)
    __builtin_amdgcn_s_barrier();
    // ---- phase 8 (last lA[1] reads); stage B(t3)->lB[1] ----
    DSREAD_AV(1, 1, 1, av)
    stageB(1, t3);
    __builtin_amdgcn_s_barrier();
    MFMA16(1, av, bv1)
    __builtin_amdgcn_s_barrier();
  }

#undef DSREAD_BV
#undef DSREAD_AV
#undef MFMA16

  // drain pending tail stages before overlaying 'part' on lA[0]
  asm volatile("s_waitcnt vmcnt(0)" ::: "memory");
  __syncthreads();

  // ---- epilogue: per-row stats, mf FULLY UNROLLED (static acc indexing) ----
  float* part = (float*)&lA[0][0];   // overlay: [256 rows][4 wn][8 floats] = 32 KB
  const bool hasdiag = (rb == ch);   // block-uniform

  int cl[4];
#pragma unroll
  for (int nf = 0; nf < 4; ++nf)
    cl[nf] = (int)LAB[colbase + wn * 64 + nf * 16 + l15];

#pragma unroll
  for (int mf = 0; mf < 8; ++mf) {
    const int lr0 = wm * 128 + mf * 16 + l4 * 4;   // local row of j=0
    int rlv[4];
#pragma unroll
    for (int j = 0; j < 4; ++j) rlv[j] = (int)LAB[rowbase + lr0 + j];

    float pe4[4], sa4[4], t54[4][5];
#pragma unroll
    for (int j = 0; j < 4; ++j) {
      pe4[j] = 0.f; sa4[j] = 0.f;
#pragma unroll
      for (int k = 0; k < 5; ++k) t54[j][k] = NEGINF;
    }

#define EPI_BODY(POSEXPR)                                      \
    _Pragma("unroll")                                          \
    for (int nf = 0; nf < 4; ++nf) {                           \
      _Pragma("unroll")                                        \
      for (int j = 0; j < 4; ++j) {                            \
        const float d = acc[mf][nf][j];                        \
        const float e = exp2f(fmaf(d, C1, -C1));               \
        const bool same = (rlv[j] == cl[nf]);                  \
        pe4[j] += (POSEXPR) ? e : 0.f;                         \
        sa4[j] += e;                                           \
        top5_insert(t54[j], same ? 0.f : d);                   \
      }                                                        \
    }

    if (hasdiag) {
      EPI_BODY(same && ((lr0 + j) != (wn * 64 + nf * 16 + l15)))
    } else {
      EPI_BODY(same)
    }
#undef EPI_BODY

    // merge the 16 lanes (l15) holding each row
#pragma unroll
    for (int j = 0; j < 4; ++j) {
#pragma unroll
      for (int msk = 1; msk < 16; msk <<= 1) {
        pe4[j] += __shfl_xor(pe4[j], msk);
        sa4[j] += __shfl_xor(sa4[j], msk);
        top5_merge_x(t54[j], msk);
      }
    }

    if (l15 == 0) {
#pragma unroll
      for (int j = 0; j < 4; ++j) {
        float4* dp = (float4*)(part + ((size_t)(lr0 + j) * 4 + wn) * 8);
        dp[0] = make_float4(pe4[j], sa4[j], t54[j][0], t54[j][1]);
        dp[1] = make_float4(t54[j][2], t54[j][3], t54[j][4], 0.f);
      }
    }
  }

  __syncthreads();

  // ---- combine the 4 wn-partials per row, write STATS ----
  if (tid < BM) {
    const float* p0 = part + (size_t)tid * 4 * 8;
    float pe = 0.f, sa = 0.f;
    float t5[5] = {NEGINF, NEGINF, NEGINF, NEGINF, NEGINF};
#pragma unroll
    for (int q = 0; q < 4; ++q) {
      const float4 a = *(const float4*)(p0 + q * 8);
      const float4 b = *(const float4*)(p0 + q * 8 + 4);
      pe += a.x; sa += a.y;
      top5_insert(t5, a.z); top5_insert(t5, a.w);
      top5_insert(t5, b.x); top5_insert(t5, b.y); top5_insert(t5, b.z);
    }
    float4* dst = (float4*)(STATS + ((size_t)(rowbase + tid) * NCHUNK + ch) * 8);
    dst[0] = make_float4(pe, sa, t5[0], t5[1]);
    dst[1] = make_float4(t5[2], t5[3], t5[4], 0.f);
  }
}

// ---------------- kernel 3: per-row finalize -> per-block partial ----------------
__global__ __launch_bounds__(256) void k_rowloss(const float* __restrict__ STATS,
                                                 const long long* __restrict__ LAB,
                                                 const float* __restrict__ DDIAG,
                                                 const int* __restrict__ HIST,
                                                 float* __restrict__ PART) {
  const int row = blockIdx.x * 256 + threadIdx.x;
  const float* sp = STATS + (size_t)row * NCHUNK * 8;
  float pe = 0.f, sa = 0.f;
  float t5[5] = {NEGINF, NEGINF, NEGINF, NEGINF, NEGINF};
  for (int c = 0; c < NCHUNK; ++c) {
    const float4 q0 = *(const float4*)(sp + c * 8);
    const float4 q1 = *(const float4*)(sp + c * 8 + 4);
    pe += q0.x; sa += q0.y;
    top5_insert(t5, q0.z); top5_insert(t5, q0.w);
    top5_insert(t5, q1.x); top5_insert(t5, q1.y); top5_insert(t5, q1.z);
  }
  const float ediag = exp2f(fmaf(DDIAG[row], C1, -C1));  // exp(s_ii - M)
  const float ne = sa - pe - ediag;                      // sum over true negatives
  const int cn = BATCH - HIST[(int)LAB[row]];            // num_neg
  const float EM = exp2f(-C1);                           // exp(0 - M)
  const float sneg = ne + (float)(BATCH - cn) * EM;      // exp_neg_sum (zeros incl.)
  const int kf = cn < 5 ? cn : 5;
  float eh[5], Sh = 0.f;
#pragma unroll
  for (int k = 0; k < 5; ++k) {
    const float dk = (k < kf) ? t5[k] : 0.f;             // top-5 as dot values
    eh[k] = exp2f(fmaf(dk, C1, -C1));                    // exp(dk*INVT - M)
    Sh += eh[k];
  }
  float lsum = 0.f;
#pragma unroll
  for (int k = 0; k < 5; ++k) {
    const float denom = pe + Sh + sneg - eh[k];
    lsum += __logf(pe / (denom + EPSV) + EPSV);
  }
#pragma unroll
  for (int m = 32; m >= 1; m >>= 1) lsum += __shfl_xor(lsum, m);
  __shared__ float wsum[4];
  if ((threadIdx.x & 63) == 0) wsum[threadIdx.x >> 6] = lsum;
  __syncthreads();
  if (threadIdx.x == 0) PART[blockIdx.x] = wsum[0] + wsum[1] + wsum[2] + wsum[3];
}

// ---------------- kernel 4: final deterministic reduce ----------------
__global__ void k_final(const float* __restrict__ PART, float* __restrict__ OUT) {
  if (threadIdx.x == 0) {
    float s = 0.f;
    for (int i = 0; i < 16; ++i) s += PART[i];
    OUT[0] = -s / (float)(BATCH * 5);
  }
}

extern "C" void kernel_launch(void* const* d_in, const int* in_sizes, int n_in,
                              void* d_out, int out_size, void* d_ws, size_t ws_size,
                              hipStream_t stream) {
  const float* X = (const float*)d_in[0];
  const long long* LAB = (const long long*)d_in[1];
  float* OUT = (float*)d_out;

  unsigned short* F = (unsigned short*)d_ws;                                   // 8 MB bf16
  float* STATS = (float*)((char*)d_ws + (size_t)8 * 1024 * 1024);              // 2 MB
  float* PART  = (float*)((char*)d_ws + (size_t)10 * 1024 * 1024);             // 64 B
  float* DDIAG = (float*)((char*)d_ws + (size_t)10 * 1024 * 1024 + 4096);      // 16 KB
  int*   HIST  = (int*)((char*)d_ws + (size_t)10 * 1024 * 1024 + 4096 + 65536); // 2 KB

  k_hist<<<1, 1024, 0, stream>>>(LAB, HIST);
  k_normalize<<<BATCH, 256, 0, stream>>>(X, F, DDIAG);
  dim3 g2(BATCH / BN, BATCH / BM);
  k_fused<<<g2, 512, 0, stream>>>(F, LAB, STATS);
  k_rowloss<<<BATCH / 256, 256, 0, stream>>>(STATS, LAB, DDIAG, HIST, PART);
  k_final<<<1, 64, 0, stream>>>(PART, OUT);
}

// Round 15
// 79.915 us; speedup vs baseline: 1.1692x; 1.1692x over previous
//
#include <hip/hip_runtime.h>
#include <hip/hip_bf16.h>

#define BATCH  4096
#define DIM    1024
#define NCHUNK 16          // 256-col chunks per row in STATS
#define BM     128
#define BN     256
#define BKK    64
#define NKT    (DIM / BKK) // 16 K-tiles
#define INVT   14.285714285714286f
#define C1     20.609929f  // INVT * log2(e); exp(INVT*(d-1)) == exp2(d*C1 - C1)
#define EPSV   1e-8f
#define NEGINF -3.0e38f

typedef __bf16 bf16x8 __attribute__((ext_vector_type(8)));
typedef float  f32x4  __attribute__((ext_vector_type(4)));
typedef __attribute__((address_space(3))) void lds_void;
typedef __attribute__((address_space(1))) void gl_void;

// Branchless sorted-desc top-5 insert (9 min/max ops).
__device__ __forceinline__ void top5_insert(float (&t)[5], float v) {
  float a = fmaxf(t[4], v), b;
  b = t[3]; t[4] = fminf(b, a); a = fmaxf(b, a);
  b = t[2]; t[3] = fminf(b, a); a = fmaxf(b, a);
  b = t[1]; t[2] = fminf(b, a); a = fmaxf(b, a);
  b = t[0]; t[1] = fminf(b, a); t[0] = fmaxf(b, a);
}

__device__ __forceinline__ void ce_desc(float& a, float& b) {
  const float hi = fmaxf(a, b), lo = fminf(a, b);
  a = hi; b = lo;
}

// Merge sorted-desc top5 with lane^msk's: elementwise max vs reversed partner
// list = top-5 multiset; 9-CE network re-sorts.
__device__ __forceinline__ void top5_merge_x(float (&t)[5], int msk) {
  const float b0 = __shfl_xor(t[0], msk);
  const float b1 = __shfl_xor(t[1], msk);
  const float b2 = __shfl_xor(t[2], msk);
  const float b3 = __shfl_xor(t[3], msk);
  const float b4 = __shfl_xor(t[4], msk);
  t[0] = fmaxf(t[0], b4); t[1] = fmaxf(t[1], b3); t[2] = fmaxf(t[2], b2);
  t[3] = fmaxf(t[3], b1); t[4] = fmaxf(t[4], b0);
  ce_desc(t[0], t[1]); ce_desc(t[3], t[4]); ce_desc(t[2], t[4]);
  ce_desc(t[2], t[3]); ce_desc(t[1], t[4]); ce_desc(t[0], t[3]);
  ce_desc(t[0], t[2]); ce_desc(t[1], t[3]); ce_desc(t[1], t[2]);
}

// ---------------- kernel 1: row L2-normalize fp32 -> bf16 (+ self-dot, + hist) ----------------
// HIST zeroed by hipMemsetAsync before this kernel; one atomicAdd per row.
__global__ __launch_bounds__(256) void k_normalize(const float* __restrict__ X,
                                                   unsigned short* __restrict__ F,
                                                   float* __restrict__ DDIAG,
                                                   int* __restrict__ HIST,
                                                   const long long* __restrict__ LAB) {
  const int row = blockIdx.x;
  const int t = threadIdx.x;
  const float4 v = ((const float4*)(X + (size_t)row * DIM))[t];
  float ss = v.x*v.x + v.y*v.y + v.z*v.z + v.w*v.w;
#pragma unroll
  for (int m = 32; m >= 1; m >>= 1) ss += __shfl_xor(ss, m);
  __shared__ float wsum[4], wsum2[4];
  if ((t & 63) == 0) wsum[t >> 6] = ss;
  __syncthreads();
  const float tot = wsum[0] + wsum[1] + wsum[2] + wsum[3];
  const float inv = 1.0f / fmaxf(sqrtf(tot), 1e-12f);
  const __bf16 b0 = (__bf16)(v.x * inv), b1 = (__bf16)(v.y * inv);
  const __bf16 b2 = (__bf16)(v.z * inv), b3 = (__bf16)(v.w * inv);
  const float f0 = (float)b0, f1 = (float)b1, f2 = (float)b2, f3 = (float)b3;
  float s2 = f0*f0 + f1*f1 + f2*f2 + f3*f3;
#pragma unroll
  for (int m = 32; m >= 1; m >>= 1) s2 += __shfl_xor(s2, m);
  if ((t & 63) == 0) wsum2[t >> 6] = s2;
  ushort4 o;
  o.x = __builtin_bit_cast(unsigned short, b0);
  o.y = __builtin_bit_cast(unsigned short, b1);
  o.z = __builtin_bit_cast(unsigned short, b2);
  o.w = __builtin_bit_cast(unsigned short, b3);
  ((ushort4*)(F + (size_t)row * DIM))[t] = o;
  __syncthreads();
  if (t == 0) {
    DDIAG[row] = wsum2[0] + wsum2[1] + wsum2[2] + wsum2[3];
    atomicAdd(&HIST[(int)LAB[row]], 1);
  }
}

// ---------------- kernel 2: fused sim GEMM + per-row stats (128x256) ----------------
// grid = (16 ch, 32 rb), 256 thr = 4 waves (2M x 2N), wave tile 64x128 =
// acc[4][8]. Single-buffered 48 KB LDS, 2-barrier loop; 2 blocks/CU
// co-residency is the latency-hiding mechanism (R10/R11 evidence; six
// intra-block schedule variants R7-R9,R13 were all null or negative).
__global__ __launch_bounds__(256, 2) void k_fused(const unsigned short* __restrict__ F,
                                                  const long long* __restrict__ LAB,
                                                  float* __restrict__ STATS) {
  __shared__ __align__(16) unsigned short lA[BM * BKK];  // 16 KB
  __shared__ __align__(16) unsigned short lB[BN * BKK];  // 32 KB

  const int ch  = blockIdx.x;
  const int rb  = blockIdx.y;
  const int tid = threadIdx.x;
  const int wid = tid >> 6;
  const int l   = tid & 63;
  const int l15 = l & 15;
  const int l4  = l >> 4;
  const int wm  = wid >> 1;        // 0..1
  const int wn  = wid & 1;         // 0..1
  const int swz = (l15 & 7) << 4;  // XOR swizzle: row%8 == l15&7 for frag reads
  const int rowbase = rb * BM;
  const int colbase = ch * BN;

  f32x4 acc[4][8];
#pragma unroll
  for (int mf = 0; mf < 4; ++mf)
#pragma unroll
    for (int nf = 0; nf < 8; ++nf) acc[mf][nf] = (f32x4){0.f, 0.f, 0.f, 0.f};

  // Precomputed staging addresses. Linear LDS dest, global source pre-swizzled
  // (16B chunk c fetched from chunk c^(r&7); involution within the 128B row).
  const unsigned short* gArow[4];
  const unsigned short* gBrow[8];
  int ldsoA[4], ldsoB[8];
#pragma unroll
  for (int it = 0; it < 4; ++it) {
    const int s = it * 256 + tid;
    const int r = s >> 3;
    const int c = (s & 7) ^ (r & 7);
    ldsoA[it] = s * 16;
    gArow[it] = F + (size_t)(rowbase + r) * DIM + c * 8;
  }
#pragma unroll
  for (int it = 0; it < 8; ++it) {
    const int s = it * 256 + tid;
    const int r = s >> 3;
    const int c = (s & 7) ^ (r & 7);
    ldsoB[it] = s * 16;
    gBrow[it] = F + (size_t)(colbase + r) * DIM + c * 8;
  }

  // ---- K loop: 2-barrier, single-buffered ----
#pragma unroll 1
  for (int kt = 0; kt < NKT; ++kt) {
    __syncthreads();                         // prev compute's LDS reads done
#pragma unroll
    for (int it = 0; it < 4; ++it)
      __builtin_amdgcn_global_load_lds((gl_void*)(gArow[it] + kt * BKK),
                                       (lds_void*)((char*)lA + ldsoA[it]), 16, 0, 0);
#pragma unroll
    for (int it = 0; it < 8; ++it)
      __builtin_amdgcn_global_load_lds((gl_void*)(gBrow[it] + kt * BKK),
                                       (lds_void*)((char*)lB + ldsoB[it]), 16, 0, 0);
    __syncthreads();                         // vmcnt(0) drain + barrier

#pragma unroll
    for (int kk = 0; kk < 2; ++kk) {
      bf16x8 av[4], bv[8];
      const int cx = (kk * 64 + l4 * 16) ^ swz;
#pragma unroll
      for (int mf = 0; mf < 4; ++mf)
        av[mf] = *(const bf16x8*)((const char*)lA + (wm * 64 + mf * 16 + l15) * 128 + cx);
#pragma unroll
      for (int nf = 0; nf < 8; ++nf)
        bv[nf] = *(const bf16x8*)((const char*)lB + (wn * 128 + nf * 16 + l15) * 128 + cx);
#pragma unroll
      for (int mf = 0; mf < 4; ++mf)
#pragma unroll
        for (int nf = 0; nf < 8; ++nf)
          acc[mf][nf] = __builtin_amdgcn_mfma_f32_16x16x32_bf16(av[mf], bv[nf], acc[mf][nf], 0, 0, 0);
    }
  }

  __syncthreads();   // all LDS reads done before part-overlay writes

  // ---- epilogue: per-row stats, mf FULLY UNROLLED (static acc indexing) ----
  float* part = (float*)lA;          // overlay: [128 rows][2 wn][8 floats] = 8 KB
  const bool hasdiag = ((rb >> 1) == ch);   // 128-row band intersects 256-col band

  int cl[8];
#pragma unroll
  for (int nf = 0; nf < 8; ++nf)
    cl[nf] = (int)LAB[colbase + wn * 128 + nf * 16 + l15];

#pragma unroll
  for (int mf = 0; mf < 4; ++mf) {
    const int lr0 = wm * 64 + mf * 16 + l4 * 4;   // local row of j=0
    int rlv[4];
#pragma unroll
    for (int j = 0; j < 4; ++j) rlv[j] = (int)LAB[rowbase + lr0 + j];

    float pe4[4], sa4[4], t54[4][5];
#pragma unroll
    for (int j = 0; j < 4; ++j) {
      pe4[j] = 0.f; sa4[j] = 0.f;
#pragma unroll
      for (int k = 0; k < 5; ++k) t54[j][k] = NEGINF;
    }

#define EPI_BODY(POSEXPR)                                      \
    _Pragma("unroll")                                          \
    for (int nf = 0; nf < 8; ++nf) {                           \
      _Pragma("unroll")                                        \
      for (int j = 0; j < 4; ++j) {                            \
        const float d = acc[mf][nf][j];                        \
        const float e = exp2f(fmaf(d, C1, -C1));               \
        const bool same = (rlv[j] == cl[nf]);                  \
        pe4[j] += (POSEXPR) ? e : 0.f;                         \
        sa4[j] += e;                                           \
        top5_insert(t54[j], same ? 0.f : d);                   \
      }                                                        \
    }

    if (hasdiag) {
      EPI_BODY(same && ((rowbase + lr0 + j) != (colbase + wn * 128 + nf * 16 + l15)))
    } else {
      EPI_BODY(same)
    }
#undef EPI_BODY

    // merge the 16 lanes (l15) holding each row
#pragma unroll
    for (int j = 0; j < 4; ++j) {
#pragma unroll
      for (int msk = 1; msk < 16; msk <<= 1) {
        pe4[j] += __shfl_xor(pe4[j], msk);
        sa4[j] += __shfl_xor(sa4[j], msk);
        top5_merge_x(t54[j], msk);
      }
    }

    if (l15 == 0) {
#pragma unroll
      for (int j = 0; j < 4; ++j) {
        float4* dp = (float4*)(part + ((size_t)(lr0 + j) * 2 + wn) * 8);
        dp[0] = make_float4(pe4[j], sa4[j], t54[j][0], t54[j][1]);
        dp[1] = make_float4(t54[j][2], t54[j][3], t54[j][4], 0.f);
      }
    }
  }

  __syncthreads();

  // ---- combine the 2 wn-partials per row, write STATS ----
  if (tid < BM) {
    const float* p0 = part + (size_t)tid * 2 * 8;
    float pe = 0.f, sa = 0.f;
    float t5[5] = {NEGINF, NEGINF, NEGINF, NEGINF, NEGINF};
#pragma unroll
    for (int q = 0; q < 2; ++q) {
      const float4 a = *(const float4*)(p0 + q * 8);
      const float4 b = *(const float4*)(p0 + q * 8 + 4);
      pe += a.x; sa += a.y;
      top5_insert(t5, a.z); top5_insert(t5, a.w);
      top5_insert(t5, b.x); top5_insert(t5, b.y); top5_insert(t5, b.z);
    }
    float4* dst = (float4*)(STATS + ((size_t)(rowbase + tid) * NCHUNK + ch) * 8);
    dst[0] = make_float4(pe, sa, t5[0], t5[1]);
    dst[1] = make_float4(t5[2], t5[3], t5[4], 0.f);
  }
}

// ---------------- kernel 3: per-row finalize + last-block final reduce ----------------
__global__ __launch_bounds__(256) void k_rowloss(const float* __restrict__ STATS,
                                                 const long long* __restrict__ LAB,
                                                 const float* __restrict__ DDIAG,
                                                 const int* __restrict__ HIST,
                                                 float* __restrict__ PART,
                                                 int* __restrict__ CNT,
                                                 float* __restrict__ OUT) {
  const int t = threadIdx.x;
  const int row = blockIdx.x * 256 + t;
  const float* sp = STATS + (size_t)row * NCHUNK * 8;
  float pe = 0.f, sa = 0.f;
  float t5[5] = {NEGINF, NEGINF, NEGINF, NEGINF, NEGINF};
  for (int c = 0; c < NCHUNK; ++c) {
    const float4 q0 = *(const float4*)(sp + c * 8);
    const float4 q1 = *(const float4*)(sp + c * 8 + 4);
    pe += q0.x; sa += q0.y;
    top5_insert(t5, q0.z); top5_insert(t5, q0.w);
    top5_insert(t5, q1.x); top5_insert(t5, q1.y); top5_insert(t5, q1.z);
  }
  const float ediag = exp2f(fmaf(DDIAG[row], C1, -C1));  // exp(s_ii - M)
  const float ne = sa - pe - ediag;                      // sum over true negatives
  const int cn = BATCH - HIST[(int)LAB[row]];            // num_neg
  const float EM = exp2f(-C1);                           // exp(0 - M)
  const float sneg = ne + (float)(BATCH - cn) * EM;      // exp_neg_sum (zeros incl.)
  const int kf = cn < 5 ? cn : 5;
  float eh[5], Sh = 0.f;
#pragma unroll
  for (int k = 0; k < 5; ++k) {
    const float dk = (k < kf) ? t5[k] : 0.f;             // top-5 as dot values
    eh[k] = exp2f(fmaf(dk, C1, -C1));                    // exp(dk*INVT - M)
    Sh += eh[k];
  }
  float lsum = 0.f;
#pragma unroll
  for (int k = 0; k < 5; ++k) {
    const float denom = pe + Sh + sneg - eh[k];
    lsum += __logf(pe / (denom + EPSV) + EPSV);
  }
#pragma unroll
  for (int m = 32; m >= 1; m >>= 1) lsum += __shfl_xor(lsum, m);
  __shared__ float wsum[4];
  if ((t & 63) == 0) wsum[t >> 6] = lsum;
  __syncthreads();

  // last-block pattern (device-scope atomics: cross-XCD coherent)
  if (t == 0) {
    const float S = wsum[0] + wsum[1] + wsum[2] + wsum[3];
    atomicExch(&PART[blockIdx.x], S);
    __threadfence();
    const int old = atomicAdd(CNT, 1);
    if (old == (int)gridDim.x - 1) {
      float s = 0.f;
#pragma unroll
      for (int i = 0; i < 16; ++i) s += atomicAdd(&PART[i], 0.f);  // coherent read
      OUT[0] = -s / (float)(BATCH * 5);
    }
  }
}

extern "C" void kernel_launch(void* const* d_in, const int* in_sizes, int n_in,
                              void* d_out, int out_size, void* d_ws, size_t ws_size,
                              hipStream_t stream) {
  const float* X = (const float*)d_in[0];
  const long long* LAB = (const long long*)d_in[1];
  float* OUT = (float*)d_out;

  unsigned short* F = (unsigned short*)d_ws;                                   // 8 MB bf16
  float* STATS = (float*)((char*)d_ws + (size_t)8 * 1024 * 1024);              // 2 MB
  float* PART  = (float*)((char*)d_ws + (size_t)12 * 1024 * 1024);             // 64 B
  float* DDIAG = (float*)((char*)d_ws + (size_t)12 * 1024 * 1024 + 4096);      // 16 KB
  char*  ZBASE = (char*)d_ws + (size_t)12 * 1024 * 1024 + 4096 + 16384;        // 4 KB zeroed
  int*   HIST  = (int*)ZBASE;                                                  // 2 KB
  int*   CNT   = (int*)(ZBASE + 2048);                                         // 4 B

  hipMemsetAsync(ZBASE, 0, 4096, stream);
  k_normalize<<<BATCH, 256, 0, stream>>>(X, F, DDIAG, HIST, LAB);
  dim3 g2(BATCH / BN, BATCH / BM);
  k_fused<<<g2, 256, 0, stream>>>(F, LAB, STATS);
  k_rowloss<<<BATCH / 256, 256, 0, stream>>>(STATS, LAB, DDIAG, HIST, PART, CNT, OUT);
}

// Round 16
// 73.074 us; speedup vs baseline: 1.2787x; 1.0936x over previous
//
#include <hip/hip_runtime.h>
#include <hip/hip_bf16.h>

#define BATCH  4096
#define DIM    1024
#define NCHUNK 16          // 256-col chunks per row in STATS
#define BM     128
#define BN     256
#define BKK    64
#define NKT    (DIM / BKK) // 16 K-tiles
#define INVT   14.285714285714286f
#define C1     20.609929f  // INVT * log2(e); exp(INVT*(d-1)) == exp2(d*C1 - C1)
#define EPSV   1e-8f
#define NEGINF -3.0e38f

typedef __bf16 bf16x8 __attribute__((ext_vector_type(8)));
typedef float  f32x4  __attribute__((ext_vector_type(4)));
typedef __attribute__((address_space(3))) void lds_void;
typedef __attribute__((address_space(1))) void gl_void;

// Branchless sorted-desc top-5 insert (9 min/max ops).
__device__ __forceinline__ void top5_insert(float (&t)[5], float v) {
  float a = fmaxf(t[4], v), b;
  b = t[3]; t[4] = fminf(b, a); a = fmaxf(b, a);
  b = t[2]; t[3] = fminf(b, a); a = fmaxf(b, a);
  b = t[1]; t[2] = fminf(b, a); a = fmaxf(b, a);
  b = t[0]; t[1] = fminf(b, a); t[0] = fmaxf(b, a);
}

__device__ __forceinline__ void ce_desc(float& a, float& b) {
  const float hi = fmaxf(a, b), lo = fminf(a, b);
  a = hi; b = lo;
}

// Merge sorted-desc top5 with lane^msk's: elementwise max vs reversed partner
// list = top-5 multiset; 9-CE network re-sorts.
__device__ __forceinline__ void top5_merge_x(float (&t)[5], int msk) {
  const float b0 = __shfl_xor(t[0], msk);
  const float b1 = __shfl_xor(t[1], msk);
  const float b2 = __shfl_xor(t[2], msk);
  const float b3 = __shfl_xor(t[3], msk);
  const float b4 = __shfl_xor(t[4], msk);
  t[0] = fmaxf(t[0], b4); t[1] = fmaxf(t[1], b3); t[2] = fmaxf(t[2], b2);
  t[3] = fmaxf(t[3], b1); t[4] = fmaxf(t[4], b0);
  ce_desc(t[0], t[1]); ce_desc(t[3], t[4]); ce_desc(t[2], t[4]);
  ce_desc(t[2], t[3]); ce_desc(t[1], t[4]); ce_desc(t[0], t[3]);
  ce_desc(t[0], t[2]); ce_desc(t[1], t[3]); ce_desc(t[1], t[2]);
}

// ---------------- kernel 0: label histogram ----------------
__global__ __launch_bounds__(1024) void k_hist(const long long* __restrict__ LAB,
                                               int* __restrict__ HIST) {
  __shared__ int h[512];
  const int t = threadIdx.x;
  if (t < 512) h[t] = 0;
  __syncthreads();
  for (int i = t; i < BATCH; i += 1024) atomicAdd(&h[(int)LAB[i]], 1);
  __syncthreads();
  if (t < 512) HIST[t] = h[t];
}

// ---------------- kernel 1: row L2-normalize fp32 -> bf16 (+ bf16 self-dot) ----------------
// Wave-per-row: 4 rows/block, pure shfl reduction (no LDS, no __syncthreads).
__global__ __launch_bounds__(256) void k_normalize(const float* __restrict__ X,
                                                   unsigned short* __restrict__ F,
                                                   float* __restrict__ DDIAG) {
  const int row = blockIdx.x * 4 + (threadIdx.x >> 6);
  const int l   = threadIdx.x & 63;
  const float4* xp = (const float4*)(X + (size_t)row * DIM);
  float4 v[4];
  float ss = 0.f;
#pragma unroll
  for (int i = 0; i < 4; ++i) {
    v[i] = xp[l + 64 * i];
    ss += v[i].x*v[i].x + v[i].y*v[i].y + v[i].z*v[i].z + v[i].w*v[i].w;
  }
#pragma unroll
  for (int m = 32; m >= 1; m >>= 1) ss += __shfl_xor(ss, m);
  const float inv = 1.0f / fmaxf(sqrtf(ss), 1e-12f);
  ushort4* fp = (ushort4*)(F + (size_t)row * DIM);
  float s2 = 0.f;
#pragma unroll
  for (int i = 0; i < 4; ++i) {
    const __bf16 b0 = (__bf16)(v[i].x * inv), b1 = (__bf16)(v[i].y * inv);
    const __bf16 b2 = (__bf16)(v[i].z * inv), b3 = (__bf16)(v[i].w * inv);
    const float f0 = (float)b0, f1 = (float)b1, f2 = (float)b2, f3 = (float)b3;
    s2 += f0*f0 + f1*f1 + f2*f2 + f3*f3;   // self-dot of bf16-rounded row
    ushort4 o;
    o.x = __builtin_bit_cast(unsigned short, b0);
    o.y = __builtin_bit_cast(unsigned short, b1);
    o.z = __builtin_bit_cast(unsigned short, b2);
    o.w = __builtin_bit_cast(unsigned short, b3);
    fp[l + 64 * i] = o;
  }
#pragma unroll
  for (int m = 32; m >= 1; m >>= 1) s2 += __shfl_xor(s2, m);
  if (l == 0) DDIAG[row] = s2;
}

// ---------------- kernel 2: fused sim GEMM + per-row stats (128x256) ----------------
// grid = (16 ch, 32 rb), 256 thr = 4 waves (2M x 2N), wave tile 64x128 =
// acc[4][8]. Single-buffered 48 KB LDS, 2-barrier loop; 2 blocks/CU
// co-residency is the latency-hiding mechanism (R10/R11 evidence; six
// intra-block schedule variants R7-R9,R13 were all null or negative).
__global__ __launch_bounds__(256, 2) void k_fused(const unsigned short* __restrict__ F,
                                                  const long long* __restrict__ LAB,
                                                  float* __restrict__ STATS) {
  __shared__ __align__(16) unsigned short lA[BM * BKK];  // 16 KB
  __shared__ __align__(16) unsigned short lB[BN * BKK];  // 32 KB

  const int ch  = blockIdx.x;
  const int rb  = blockIdx.y;
  const int tid = threadIdx.x;
  const int wid = tid >> 6;
  const int l   = tid & 63;
  const int l15 = l & 15;
  const int l4  = l >> 4;
  const int wm  = wid >> 1;        // 0..1
  const int wn  = wid & 1;         // 0..1
  const int swz = (l15 & 7) << 4;  // XOR swizzle: row%8 == l15&7 for frag reads
  const int rowbase = rb * BM;
  const int colbase = ch * BN;

  f32x4 acc[4][8];
#pragma unroll
  for (int mf = 0; mf < 4; ++mf)
#pragma unroll
    for (int nf = 0; nf < 8; ++nf) acc[mf][nf] = (f32x4){0.f, 0.f, 0.f, 0.f};

  // Precomputed staging addresses. Linear LDS dest, global source pre-swizzled
  // (16B chunk c fetched from chunk c^(r&7); involution within the 128B row).
  const unsigned short* gArow[4];
  const unsigned short* gBrow[8];
  int ldsoA[4], ldsoB[8];
#pragma unroll
  for (int it = 0; it < 4; ++it) {
    const int s = it * 256 + tid;
    const int r = s >> 3;
    const int c = (s & 7) ^ (r & 7);
    ldsoA[it] = s * 16;
    gArow[it] = F + (size_t)(rowbase + r) * DIM + c * 8;
  }
#pragma unroll
  for (int it = 0; it < 8; ++it) {
    const int s = it * 256 + tid;
    const int r = s >> 3;
    const int c = (s & 7) ^ (r & 7);
    ldsoB[it] = s * 16;
    gBrow[it] = F + (size_t)(colbase + r) * DIM + c * 8;
  }

  // ---- K loop: 2-barrier, single-buffered ----
#pragma unroll 1
  for (int kt = 0; kt < NKT; ++kt) {
    __syncthreads();                         // prev compute's LDS reads done
#pragma unroll
    for (int it = 0; it < 4; ++it)
      __builtin_amdgcn_global_load_lds((gl_void*)(gArow[it] + kt * BKK),
                                       (lds_void*)((char*)lA + ldsoA[it]), 16, 0, 0);
#pragma unroll
    for (int it = 0; it < 8; ++it)
      __builtin_amdgcn_global_load_lds((gl_void*)(gBrow[it] + kt * BKK),
                                       (lds_void*)((char*)lB + ldsoB[it]), 16, 0, 0);
    __syncthreads();                         // vmcnt(0) drain + barrier

#pragma unroll
    for (int kk = 0; kk < 2; ++kk) {
      bf16x8 av[4], bv[8];
      const int cx = (kk * 64 + l4 * 16) ^ swz;
#pragma unroll
      for (int mf = 0; mf < 4; ++mf)
        av[mf] = *(const bf16x8*)((const char*)lA + (wm * 64 + mf * 16 + l15) * 128 + cx);
#pragma unroll
      for (int nf = 0; nf < 8; ++nf)
        bv[nf] = *(const bf16x8*)((const char*)lB + (wn * 128 + nf * 16 + l15) * 128 + cx);
#pragma unroll
      for (int mf = 0; mf < 4; ++mf)
#pragma unroll
        for (int nf = 0; nf < 8; ++nf)
          acc[mf][nf] = __builtin_amdgcn_mfma_f32_16x16x32_bf16(av[mf], bv[nf], acc[mf][nf], 0, 0, 0);
    }
  }

  __syncthreads();   // all LDS reads done before part-overlay writes

  // ---- epilogue: per-row stats, mf FULLY UNROLLED (static acc indexing) ----
  float* part = (float*)lA;          // overlay: [128 rows][2 wn][8 floats] = 8 KB
  const bool hasdiag = ((rb >> 1) == ch);   // 128-row band intersects 256-col band

  int cl[8];
#pragma unroll
  for (int nf = 0; nf < 8; ++nf)
    cl[nf] = (int)LAB[colbase + wn * 128 + nf * 16 + l15];

#pragma unroll
  for (int mf = 0; mf < 4; ++mf) {
    const int lr0 = wm * 64 + mf * 16 + l4 * 4;   // local row of j=0
    int rlv[4];
#pragma unroll
    for (int j = 0; j < 4; ++j) rlv[j] = (int)LAB[rowbase + lr0 + j];

    float pe4[4], sa4[4], t54[4][5];
#pragma unroll
    for (int j = 0; j < 4; ++j) {
      pe4[j] = 0.f; sa4[j] = 0.f;
#pragma unroll
      for (int k = 0; k < 5; ++k) t54[j][k] = NEGINF;
    }

#define EPI_BODY(POSEXPR)                                      \
    _Pragma("unroll")                                          \
    for (int nf = 0; nf < 8; ++nf) {                           \
      _Pragma("unroll")                                        \
      for (int j = 0; j < 4; ++j) {                            \
        const float d = acc[mf][nf][j];                        \
        const float e = exp2f(fmaf(d, C1, -C1));               \
        const bool same = (rlv[j] == cl[nf]);                  \
        pe4[j] += (POSEXPR) ? e : 0.f;                         \
        sa4[j] += e;                                           \
        top5_insert(t54[j], same ? 0.f : d);                   \
      }                                                        \
    }

    if (hasdiag) {
      EPI_BODY(same && ((rowbase + lr0 + j) != (colbase + wn * 128 + nf * 16 + l15)))
    } else {
      EPI_BODY(same)
    }
#undef EPI_BODY

    // merge the 16 lanes (l15) holding each row
#pragma unroll
    for (int j = 0; j < 4; ++j) {
#pragma unroll
      for (int msk = 1; msk < 16; msk <<= 1) {
        pe4[j] += __shfl_xor(pe4[j], msk);
        sa4[j] += __shfl_xor(sa4[j], msk);
        top5_merge_x(t54[j], msk);
      }
    }

    if (l15 == 0) {
#pragma unroll
      for (int j = 0; j < 4; ++j) {
        float4* dp = (float4*)(part + ((size_t)(lr0 + j) * 2 + wn) * 8);
        dp[0] = make_float4(pe4[j], sa4[j], t54[j][0], t54[j][1]);
        dp[1] = make_float4(t54[j][2], t54[j][3], t54[j][4], 0.f);
      }
    }
  }

  __syncthreads();

  // ---- combine the 2 wn-partials per row, write STATS ----
  if (tid < BM) {
    const float* p0 = part + (size_t)tid * 2 * 8;
    float pe = 0.f, sa = 0.f;
    float t5[5] = {NEGINF, NEGINF, NEGINF, NEGINF, NEGINF};
#pragma unroll
    for (int q = 0; q < 2; ++q) {
      const float4 a = *(const float4*)(p0 + q * 8);
      const float4 b = *(const float4*)(p0 + q * 8 + 4);
      pe += a.x; sa += a.y;
      top5_insert(t5, a.z); top5_insert(t5, a.w);
      top5_insert(t5, b.x); top5_insert(t5, b.y); top5_insert(t5, b.z);
    }
    float4* dst = (float4*)(STATS + ((size_t)(rowbase + tid) * NCHUNK + ch) * 8);
    dst[0] = make_float4(pe, sa, t5[0], t5[1]);
    dst[1] = make_float4(t5[2], t5[3], t5[4], 0.f);
  }
}

// ---------------- kernel 3: per-row finalize -> per-block partial ----------------
__global__ __launch_bounds__(256) void k_rowloss(const float* __restrict__ STATS,
                                                 const long long* __restrict__ LAB,
                                                 const float* __restrict__ DDIAG,
                                                 const int* __restrict__ HIST,
                                                 float* __restrict__ PART) {
  const int row = blockIdx.x * 256 + threadIdx.x;
  const float* sp = STATS + (size_t)row * NCHUNK * 8;
  float pe = 0.f, sa = 0.f;
  float t5[5] = {NEGINF, NEGINF, NEGINF, NEGINF, NEGINF};
  for (int c = 0; c < NCHUNK; ++c) {
    const float4 q0 = *(const float4*)(sp + c * 8);
    const float4 q1 = *(const float4*)(sp + c * 8 + 4);
    pe += q0.x; sa += q0.y;
    top5_insert(t5, q0.z); top5_insert(t5, q0.w);
    top5_insert(t5, q1.x); top5_insert(t5, q1.y); top5_insert(t5, q1.z);
  }
  const float ediag = exp2f(fmaf(DDIAG[row], C1, -C1));  // exp(s_ii - M)
  const float ne = sa - pe - ediag;                      // sum over true negatives
  const int cn = BATCH - HIST[(int)LAB[row]];            // num_neg
  const float EM = exp2f(-C1);                           // exp(0 - M)
  const float sneg = ne + (float)(BATCH - cn) * EM;      // exp_neg_sum (zeros incl.)
  const int kf = cn < 5 ? cn : 5;
  float eh[5], Sh = 0.f;
#pragma unroll
  for (int k = 0; k < 5; ++k) {
    const float dk = (k < kf) ? t5[k] : 0.f;             // top-5 as dot values
    eh[k] = exp2f(fmaf(dk, C1, -C1));                    // exp(dk*INVT - M)
    Sh += eh[k];
  }
  float lsum = 0.f;
#pragma unroll
  for (int k = 0; k < 5; ++k) {
    const float denom = pe + Sh + sneg - eh[k];
    lsum += __logf(pe / (denom + EPSV) + EPSV);
  }
#pragma unroll
  for (int m = 32; m >= 1; m >>= 1) lsum += __shfl_xor(lsum, m);
  __shared__ float wsum[4];
  if ((threadIdx.x & 63) == 0) wsum[threadIdx.x >> 6] = lsum;
  __syncthreads();
  if (threadIdx.x == 0) PART[blockIdx.x] = wsum[0] + wsum[1] + wsum[2] + wsum[3];
}

// ---------------- kernel 4: final deterministic reduce ----------------
__global__ void k_final(const float* __restrict__ PART, float* __restrict__ OUT) {
  if (threadIdx.x == 0) {
    float s = 0.f;
    for (int i = 0; i < 16; ++i) s += PART[i];
    OUT[0] = -s / (float)(BATCH * 5);
  }
}

extern "C" void kernel_launch(void* const* d_in, const int* in_sizes, int n_in,
                              void* d_out, int out_size, void* d_ws, size_t ws_size,
                              hipStream_t stream) {
  const float* X = (const float*)d_in[0];
  const long long* LAB = (const long long*)d_in[1];
  float* OUT = (float*)d_out;

  unsigned short* F = (unsigned short*)d_ws;                                   // 8 MB bf16
  float* STATS = (float*)((char*)d_ws + (size_t)8 * 1024 * 1024);              // 2 MB
  float* PART  = (float*)((char*)d_ws + (size_t)12 * 1024 * 1024);             // 64 B
  float* DDIAG = (float*)((char*)d_ws + (size_t)12 * 1024 * 1024 + 4096);      // 16 KB
  int*   HIST  = (int*)((char*)d_ws + (size_t)12 * 1024 * 1024 + 4096 + 16384); // 2 KB

  k_hist<<<1, 1024, 0, stream>>>(LAB, HIST);
  k_normalize<<<BATCH / 4, 256, 0, stream>>>(X, F, DDIAG);
  dim3 g2(BATCH / BN, BATCH / BM);
  k_fused<<<g2, 256, 0, stream>>>(F, LAB, STATS);
  k_rowloss<<<BATCH / 256, 256, 0, stream>>>(STATS, LAB, DDIAG, HIST, PART);
  k_final<<<1, 64, 0, stream>>>(PART, OUT);
}